// Round 7
// baseline (394.352 us; speedup 1.0000x reference)
//
#include <hip/hip_runtime.h>
#include <hip/hip_bf16.h>
#include <stdint.h>

#define G_ 8
#define T_ 1024
#define K_ 7168
#define N_ 2048
#define KB_ 56         // K/128 quant blocks
#define NB_ 16         // N/128
#define NT8_ 56        // K-tiles of 128

typedef __attribute__((ext_vector_type(4))) float f32x4;
typedef __attribute__((ext_vector_type(8))) int   i32x8;

typedef __attribute__((address_space(3))) uint32_t lds_u32_t;
typedef const __attribute__((address_space(1))) uint32_t gbl_u32_t;

__device__ __forceinline__ void gload_lds16(const void* gsrc, const void* ldst)
{
    __builtin_amdgcn_global_load_lds(
        (gbl_u32_t*)(uintptr_t)gsrc,
        (lds_u32_t*)(uint32_t)(uintptr_t)ldst, 16, 0, 0);
}

__device__ __forceinline__ void blockbar()
{
    asm volatile("" ::: "memory");
    __builtin_amdgcn_s_barrier();
    asm volatile("" ::: "memory");
}

// ---------------------------------------------------------------------------
// Kernel 1: activation quant -> fp8 bytes + scale table.
//   scale layout: [g][t>>8][kb][t&255]
// ---------------------------------------------------------------------------
__global__ __launch_bounds__(256) void act_quant_kernel(
    const float* __restrict__ xs, uint8_t* __restrict__ xq8,
    float* __restrict__ ascale)
{
    const int grp = (blockIdx.x * 256 + threadIdx.x) >> 5;
    const int l   = threadIdx.x & 31;
    const size_t base = (size_t)grp * 128 + (size_t)l * 4;

    const float4 v = *(const float4*)(xs + base);
    float am = fmaxf(fmaxf(fabsf(v.x), fabsf(v.y)),
                     fmaxf(fabsf(v.z), fabsf(v.w)));
#pragma unroll
    for (int off = 1; off <= 16; off <<= 1)
        am = fmaxf(am, __shfl_xor(am, off, 64));

    const float rs = 448.0f / am;
    const float s  = am * (1.0f / 448.0f);

    int pk = __builtin_amdgcn_cvt_pk_fp8_f32(v.x * rs, v.y * rs, 0, false);
    pk     = __builtin_amdgcn_cvt_pk_fp8_f32(v.z * rs, v.w * rs, pk, true);
    *(uint32_t*)(xq8 + base) = (uint32_t)pk;

    if (l == 0) {
        const int kb = grp % KB_;
        const int t  = (grp / KB_) & (T_ - 1);
        const int g  = grp / (KB_ * T_);
        ascale[(((size_t)(g * 4 + (t >> 8))) * KB_ + kb) * 256 + (t & 255)] = s;
    }
}

// ---------------------------------------------------------------------------
// Kernel 2: blockwise-fp8 grouped GEMM, FUSED in-loop weight recode.
//   128x128 tile, BK=128, 4 waves, 2 blocks/CU, 1 barrier/K-tile.
//   A fp8: global_load_lds (pre-swizzled source). B: coalesced fp32 code
//   loads -> cvt_pk_fp8 -> swizzled ds_write_b32 after the MFMA block.
//   mfma_scale_f32_16x16x128_f8f6f4 (unit E8M0) + per-block fp32 rescale.
//   LDS: A 2x16K @0 | B 2x16K @32768 | ascale 2x4K @65536 | wscale @73728.
// ---------------------------------------------------------------------------
union Frag { i32x8 v; struct { int4 lo, hi; } p; };

#define RD_FRAG(dst, base, r)                                                 \
  { const int rx_ = ((r) & 7) << 4;                                           \
    const char* bp_ = smem + (base) + (r)*128;                                \
    dst.p.lo = *(const int4*)(bp_ + ((lhi*32) ^ rx_));                        \
    dst.p.hi = *(const int4*)(bp_ + ((lhi*32 + 16) ^ rx_)); }

#define STG_A(c, t, bb) gload_lds16(pA8[c] + (size_t)(t)*128,                 \
      smem + (bb)*16384 + (c)*4096 + tid*16)
#define STG_S(c) gload_lds16(pS + (size_t)(c)*2048,                           \
      smem + 65536 + ((c)&1)*4096 + tid*16)

// issue 16 coalesced fp32-code loads for next B tile (wave: 2x512B rows/instr)
#define LOAD_B(t)                                                             \
  { _Pragma("unroll") for (int i = 0; i < 16; ++i)                            \
      br[i] = *(const f32x4*)(pWb + (size_t)(t)*128 + (size_t)i*(2*K_)); }

// convert staged regs -> fp8, swizzled ds_write_b32 into B buf bb
#define CVT_WRITE_B(bb)                                                       \
  { _Pragma("unroll") for (int i = 0; i < 16; ++i) {                          \
      int pk_ = __builtin_amdgcn_cvt_pk_fp8_f32(br[i][0], br[i][1], 0, false);\
      pk_ = __builtin_amdgcn_cvt_pk_fp8_f32(br[i][2], br[i][3], pk_, true);   \
      const int r_ = wid*32 + i*2 + lp;                                       \
      *(uint32_t*)(smem + 32768 + (bb)*16384 + r_*128 +                       \
          (((l31 >> 2) ^ (r_ & 7)) << 4) + (l31 & 3)*4) = (uint32_t)pk_;      \
  } }

__global__ __launch_bounds__(256, 2) void gemm_fp8_kernel(
    const uint8_t* __restrict__ xq8, const float* __restrict__ w,
    const float* __restrict__ ascale, const float* __restrict__ wscale,
    const float* __restrict__ bias, float* __restrict__ y)
{
    __shared__ char smem[73984];

    const int bx0 = blockIdx.x;
    const int g     = bx0 & 7;          // group == XCD (L2 w-slab sharing)
    const int inner = bx0 >> 3;         // 0..127
    const int tn    = inner >> 3;       // 0..15
    const int tm    = inner & 7;        // 0..7
    const int t0 = tm * 128, n0 = tn * 128;

    const int tid = threadIdx.x, lane = tid & 63, wid = tid >> 6;
    const int l15 = lane & 15, lhi = lane >> 4;
    const int l31 = lane & 31, lp = lane >> 5;
    const int wrow = (wid >> 1) * 64;
    const int wcol = (wid & 1) * 64;

    const uint8_t* Ag = xq8 + (size_t)g * T_ * K_;
    const float*   Wg = w   + (size_t)g * N_ * K_;

    // A staging map: LDS(row = c*32 + tid/8, slot = tid&7) <- global slot^row&7
    const uint8_t* pA8[4];
#pragma unroll
    for (int c = 0; c < 4; ++c)
        pA8[c] = Ag + (size_t)(t0 + c * 32 + (tid >> 3)) * K_
                    + ((tid & 7) ^ ((tid >> 3) & 7)) * 16;

    // B fp32 base: wave w, row-parity lp, floats (l31*4 ..)
    const float* pWb = Wg + (size_t)(n0 + wid * 32 + lp) * K_ + l31 * 4;

    // ascale chunk source (8 kb x 128 tokens = 4KB)
    const float* pS = ascale + ((size_t)(g * 4 + (tm >> 1)) * KB_) * 256
                    + (tid >> 5) * 256 + (tm & 1) * 128 + (tid & 31) * 4;

    const f32x4 z4 = {0.f, 0.f, 0.f, 0.f};
    f32x4 acc[4][4] = {};
    Frag bF[4];
    f32x4 br[16];

    // ---- prologue: wscale row, B tile0 (reg-cvt), A tile0, ascale chunk0 ----
    if (tid < KB_) {
        const float wv = wscale[((size_t)(g * NB_ + tn)) * KB_ + tid];
        *(float*)(smem + 73728 + tid * 4) = wv;
    }
    LOAD_B(0);
    asm volatile("s_waitcnt vmcnt(0)" ::: "memory");
    CVT_WRITE_B(0);
#pragma unroll
    for (int c = 0; c < 4; ++c) STG_A(c, 0, 0);
    STG_S(0);
    asm volatile("s_waitcnt vmcnt(0)" ::: "memory");
    asm volatile("s_waitcnt lgkmcnt(0)" ::: "memory");
    blockbar();

    for (int u = 0; u < NT8_; ++u) {
        const int cur = u & 1, nxt = cur ^ 1;
        const bool pf = (u + 1 < NT8_);
        const int abuf = (u >> 3) & 1;

        // ---- stage issue: [ascale chunk]; B-regs(u+1); A-glds(u+1) ----
        if ((u & 7) == 0 && u + 8 < NT8_) STG_S((u >> 3) + 1);
        if (pf) {
            LOAD_B(u + 1);
#pragma unroll
            for (int c = 0; c < 4; ++c) STG_A(c, u + 1, nxt);
        }

        const float wsc = *(const float*)(smem + 73728 + u * 4);

        // ---- B frags from LDS[cur] ----
#pragma unroll
        for (int n = 0; n < 4; ++n)
            RD_FRAG(bF[n], 32768 + cur * 16384, wcol + n * 16 + l15);

        asm volatile("s_waitcnt lgkmcnt(0)" ::: "memory");
        __builtin_amdgcn_s_setprio(1);
#pragma unroll
        for (int m = 0; m < 4; ++m) {
            Frag aF;
            const int r = wrow + m * 16 + l15;
            RD_FRAG(aF, cur * 16384, r);
            const float4 sv = *(const float4*)(smem + 65536 + abuf * 4096 +
                (u & 7) * 512 + (wrow + m * 16 + lhi * 4) * 4);
            const float a0 = sv.x * wsc, a1 = sv.y * wsc,
                        a2 = sv.z * wsc, a3 = sv.w * wsc;
#pragma unroll
            for (int n = 0; n < 4; ++n) {
                f32x4 blk = __builtin_amdgcn_mfma_scale_f32_16x16x128_f8f6f4(
                    aF.v, bF[n].v, z4, 0, 0, 0, 0x7F7F7F7F, 0, 0x7F7F7F7F);
                acc[m][n][0] += blk[0] * a0;
                acc[m][n][1] += blk[1] * a1;
                acc[m][n][2] += blk[2] * a2;
                acc[m][n][3] += blk[3] * a3;
            }
        }
        __builtin_amdgcn_s_setprio(0);

        // ---- convert B(u+1) under no contention; drain; barrier ----
        if (pf) {
            asm volatile("s_waitcnt vmcnt(4)" ::: "memory");  // br landed
            CVT_WRITE_B(nxt);
            asm volatile("s_waitcnt vmcnt(0)" ::: "memory");  // A-glds landed
            asm volatile("s_waitcnt lgkmcnt(0)" ::: "memory");// ds_writes done
            blockbar();
        }
    }

    // ---- epilogue: C/D layout col = lane&15, row = (lane>>4)*4 + j ----
    float* Yg = y + (size_t)g * T_ * N_;
#pragma unroll
    for (int n = 0; n < 4; ++n) {
        const int col = n0 + wcol + n * 16 + l15;
        const float bv = bias[g * N_ + col];
#pragma unroll
        for (int m = 0; m < 4; ++m) {
            const int r0 = t0 + wrow + m * 16 + lhi * 4;
#pragma unroll
            for (int j = 0; j < 4; ++j)
                Yg[(size_t)(r0 + j) * N_ + col] = acc[m][n][j] + bv;
        }
    }
}

// ---------------------------------------------------------------------------
extern "C" void kernel_launch(void* const* d_in, const int* in_sizes, int n_in,
                              void* d_out, int out_size, void* d_ws, size_t ws_size,
                              hipStream_t stream)
{
    const float* xs     = (const float*)d_in[0];
    const float* weight = (const float*)d_in[1];
    const float* scale  = (const float*)d_in[2];
    const float* bias   = (const float*)d_in[3];
    float* y = (float*)d_out;

    uint8_t* xq8  = (uint8_t*)d_ws;                      // 58,720,256 B
    float*   ascl = (float*)((char*)d_ws + 58720256);    //  1,835,008 B

    act_quant_kernel<<<(G_ * T_ * KB_) / 8, 256, 0, stream>>>(xs, xq8, ascl);
    gemm_fp8_kernel<<<G_ * (T_ / 128) * (N_ / 128), 256, 0, stream>>>(
        xq8, weight, ascl, scale, bias, y);
}

// Round 8
// 340.163 us; speedup vs baseline: 1.1593x; 1.1593x over previous
//
#include <hip/hip_runtime.h>
#include <hip/hip_bf16.h>
#include <stdint.h>

#define G_ 8
#define T_ 1024
#define K_ 7168
#define N_ 2048
#define KB_ 56         // K/128 quant blocks
#define NB_ 16         // N/128
#define NT8_ 56        // K-tiles of 128

#define ACT_WGS  57344   // (G*T*KB)/8
#define WREC_WGS 28672   // (G*N*K/16)/256

typedef __attribute__((ext_vector_type(4))) float f32x4;
typedef __attribute__((ext_vector_type(8))) int   i32x8;

typedef __attribute__((address_space(3))) uint32_t lds_u32_t;
typedef const __attribute__((address_space(1))) uint32_t gbl_u32_t;

__device__ __forceinline__ void gload_lds16(const void* gsrc, const void* ldst)
{
    __builtin_amdgcn_global_load_lds(
        (gbl_u32_t*)(uintptr_t)gsrc,
        (lds_u32_t*)(uint32_t)(uintptr_t)ldst, 16, 0, 0);
}

__device__ __forceinline__ void blockbar()
{
    asm volatile("" ::: "memory");
    __builtin_amdgcn_s_barrier();
    asm volatile("" ::: "memory");
}

// ---------------------------------------------------------------------------
// Kernel 1: fused prepass (round-6, verified).
//   Blocks [0, ACT_WGS): act quant -> fp8 bytes + scale table
//   Blocks [ACT_WGS, ..): weight recode fp32-held-codes -> fp8 bytes
// ---------------------------------------------------------------------------
__global__ __launch_bounds__(256) void prep_kernel(
    const float* __restrict__ xs, uint8_t* __restrict__ xq8,
    float* __restrict__ ascale,
    const float* __restrict__ w, uint8_t* __restrict__ wq8)
{
    const int bid = blockIdx.x;
    if (bid < ACT_WGS) {
        const int grp = (bid * 256 + threadIdx.x) >> 5;
        const int l   = threadIdx.x & 31;
        const size_t base = (size_t)grp * 128 + (size_t)l * 4;

        const float4 v = *(const float4*)(xs + base);
        float am = fmaxf(fmaxf(fabsf(v.x), fabsf(v.y)),
                         fmaxf(fabsf(v.z), fabsf(v.w)));
#pragma unroll
        for (int off = 1; off <= 16; off <<= 1)
            am = fmaxf(am, __shfl_xor(am, off, 64));

        const float rs = 448.0f / am;
        const float s  = am * (1.0f / 448.0f);

        int pk = __builtin_amdgcn_cvt_pk_fp8_f32(v.x * rs, v.y * rs, 0, false);
        pk     = __builtin_amdgcn_cvt_pk_fp8_f32(v.z * rs, v.w * rs, pk, true);
        *(uint32_t*)(xq8 + base) = (uint32_t)pk;

        if (l == 0) {
            const int kb = grp % KB_;
            const int t  = (grp / KB_) & (T_ - 1);
            const int g  = grp / (KB_ * T_);
            ascale[(((size_t)(g * 4 + (t >> 8))) * KB_ + kb) * 256 + (t & 255)] = s;
        }
    } else {
        const size_t i = ((size_t)(bid - ACT_WGS) * 256 + threadIdx.x) * 16;
        uint32_t o[4];
#pragma unroll
        for (int q = 0; q < 4; ++q) {
            const float4 a = *(const float4*)(w + i + q * 4);
            int pk = __builtin_amdgcn_cvt_pk_fp8_f32(a.x, a.y, 0, false);
            pk     = __builtin_amdgcn_cvt_pk_fp8_f32(a.z, a.w, pk, true);
            o[q] = (uint32_t)pk;
        }
        *(uint4*)(wq8 + i) = make_uint4(o[0], o[1], o[2], o[3]);
    }
}

// ---------------------------------------------------------------------------
// Kernel 2: blockwise-fp8 grouped GEMM, 128x128 tile, BK=128, 4 waves,
//   2 blocks/CU, ONE barrier + one vmcnt(0) per K-tile (T3-minimum; the
//   co-resident block covers drains). A+B fp8 via global_load_lds with
//   XOR-swizzled sources. mfma_scale 16x16x128 f8f6f4 (unit E8M0) +
//   per-block fp32 rescale.
//   LDS: A 2x16K @0 | B 2x16K @32768 | ascale 2x4K @65536 | wscale @73728.
// ---------------------------------------------------------------------------
union Frag { i32x8 v; struct { int4 lo, hi; } p; };

#define RD_FRAG(dst, base, r)                                                 \
  { const int rx_ = ((r) & 7) << 4;                                           \
    const char* bp_ = smem + (base) + (r)*128;                                \
    dst.p.lo = *(const int4*)(bp_ + ((lhi*32) ^ rx_));                        \
    dst.p.hi = *(const int4*)(bp_ + ((lhi*32 + 16) ^ rx_)); }

#define STG_A(c, t, bb) gload_lds16(pA8[c] + (size_t)(t)*128,                 \
      smem + (bb)*16384 + (c)*4096 + tid*16)
#define STG_B(c, t, bb) gload_lds16(pB8[c] + (size_t)(t)*128,                 \
      smem + 32768 + (bb)*16384 + (c)*4096 + tid*16)
#define STG_S(c) gload_lds16(pS + (size_t)(c)*2048,                           \
      smem + 65536 + ((c)&1)*4096 + tid*16)

__global__ __launch_bounds__(256, 2) void gemm_fp8_kernel(
    const uint8_t* __restrict__ xq8, const uint8_t* __restrict__ wq8,
    const float* __restrict__ ascale, const float* __restrict__ wscale,
    const float* __restrict__ bias, float* __restrict__ y)
{
    __shared__ char smem[73952];

    const int bx0 = blockIdx.x;
    const int g     = bx0 & 7;          // group == XCD (L2 slab sharing)
    const int inner = bx0 >> 3;         // 0..127
    const int tn    = inner & 15;       // 0..15
    const int tm    = inner >> 4;       // 0..7
    const int t0 = tm * 128, n0 = tn * 128;

    const int tid = threadIdx.x, lane = tid & 63, wid = tid >> 6;
    const int l15 = lane & 15, lhi = lane >> 4;
    const int wrow = (wid >> 1) * 64;
    const int wcol = (wid & 1) * 64;

    const uint8_t* Ag = xq8 + (size_t)g * T_ * K_;
    const uint8_t* Bg = wq8 + (size_t)g * N_ * K_;

    // staging maps: LDS(row = c*32 + tid/8, slot = tid&7) <- global slot^row&7
    const int srow = tid >> 3;
    const int xoff = ((tid & 7) ^ (srow & 7)) * 16;
    const uint8_t* pA8[4];
    const uint8_t* pB8[4];
#pragma unroll
    for (int c = 0; c < 4; ++c) {
        pA8[c] = Ag + (size_t)(t0 + c * 32 + srow) * K_ + xoff;
        pB8[c] = Bg + (size_t)(n0 + c * 32 + srow) * K_ + xoff;
    }

    // ascale chunk source: 8 kb x 128 tokens = 4KB per chunk
    const float* pS = ascale + ((size_t)(g * 4 + (tm >> 1)) * KB_) * 256
                    + (tid >> 5) * 256 + (tm & 1) * 128 + (tid & 31) * 4;

    const f32x4 z4 = {0.f, 0.f, 0.f, 0.f};
    f32x4 acc[4][4] = {};
    Frag bF[4];

    // ---- prologue: wscale row, ascale chunk 0, tile 0 -> buf0 ----
    if (tid < KB_) {
        const float wv = wscale[((size_t)(g * NB_ + tn)) * KB_ + tid];
        *(float*)(smem + 73728 + tid * 4) = wv;
    }
    STG_S(0);
#pragma unroll
    for (int c = 0; c < 4; ++c) { STG_A(c, 0, 0); STG_B(c, 0, 0); }
    asm volatile("s_waitcnt vmcnt(0)" ::: "memory");
    asm volatile("s_waitcnt lgkmcnt(0)" ::: "memory");
    blockbar();

    for (int u = 0; u < NT8_; ++u) {
        const int cur = u & 1, nxt = cur ^ 1;
        const bool pf = (u + 1 < NT8_);
        const int sbuf = (u >> 3) & 1;

        // ---- stage issue first (T3): [ascale chunk]; A+B tile u+1 ----
        if ((u & 7) == 0 && u + 8 < NT8_) STG_S((u >> 3) + 1);
        if (pf) {
#pragma unroll
            for (int c = 0; c < 4; ++c) { STG_A(c, u + 1, nxt); STG_B(c, u + 1, nxt); }
        }

        const float wsc = *(const float*)(smem + 73728 + u * 4);

        // ---- B frags from LDS[cur] ----
#pragma unroll
        for (int n = 0; n < 4; ++n)
            RD_FRAG(bF[n], 32768 + cur * 16384, wcol + n * 16 + l15);

        // ---- MFMA + per-block rescale ----
        __builtin_amdgcn_s_setprio(1);
#pragma unroll
        for (int m = 0; m < 4; ++m) {
            Frag aF;
            RD_FRAG(aF, cur * 16384, wrow + m * 16 + l15);
            const float4 sv = *(const float4*)(smem + 65536 + sbuf * 4096 +
                (u & 7) * 512 + (wrow + m * 16 + lhi * 4) * 4);
            const float a0 = sv.x * wsc, a1 = sv.y * wsc,
                        a2 = sv.z * wsc, a3 = sv.w * wsc;
#pragma unroll
            for (int n = 0; n < 4; ++n) {
                f32x4 blk = __builtin_amdgcn_mfma_scale_f32_16x16x128_f8f6f4(
                    aF.v, bF[n].v, z4, 0, 0, 0, 0x7F7F7F7F, 0, 0x7F7F7F7F);
                acc[m][n][0] += blk[0] * a0;
                acc[m][n][1] += blk[1] * a1;
                acc[m][n][2] += blk[2] * a2;
                acc[m][n][3] += blk[3] * a3;
            }
        }
        __builtin_amdgcn_s_setprio(0);

        // ---- single drain + barrier per K-tile ----
        if (pf) {
            asm volatile("s_waitcnt vmcnt(0)" ::: "memory");
            blockbar();
        }
    }

    // ---- epilogue: C/D layout col = lane&15, row = (lane>>4)*4 + j ----
    float* Yg = y + (size_t)g * T_ * N_;
#pragma unroll
    for (int n = 0; n < 4; ++n) {
        const int col = n0 + wcol + n * 16 + l15;
        const float bv = bias[g * N_ + col];
#pragma unroll
        for (int m = 0; m < 4; ++m) {
            const int r0 = t0 + wrow + m * 16 + lhi * 4;
#pragma unroll
            for (int j = 0; j < 4; ++j)
                Yg[(size_t)(r0 + j) * N_ + col] = acc[m][n][j] + bv;
        }
    }
}

// ---------------------------------------------------------------------------
extern "C" void kernel_launch(void* const* d_in, const int* in_sizes, int n_in,
                              void* d_out, int out_size, void* d_ws, size_t ws_size,
                              hipStream_t stream)
{
    const float* xs     = (const float*)d_in[0];
    const float* weight = (const float*)d_in[1];
    const float* scale  = (const float*)d_in[2];
    const float* bias   = (const float*)d_in[3];
    float* y = (float*)d_out;

    uint8_t* xq8  = (uint8_t*)d_ws;                      //  58,720,256 B
    float*   ascl = (float*)((char*)d_ws + 58720256);    //   1,835,008 B
    uint8_t* wq8  = (uint8_t*)((char*)d_ws + 60555264);  // 117,440,512 B

    prep_kernel<<<ACT_WGS + WREC_WGS, 256, 0, stream>>>(
        xs, xq8, ascl, weight, wq8);

    gemm_fp8_kernel<<<G_ * (T_ / 128) * (N_ / 128), 256, 0, stream>>>(
        xq8, wq8, ascl, scale, bias, y);
}